// Round 4
// baseline (112.697 us; speedup 1.0000x reference)
//
#include <hip/hip_runtime.h>

#define NB 4
#define NN 256
#define ND 512
#define NITER 10

typedef __attribute__((ext_vector_type(8))) unsigned short ushort8v;

__device__ __forceinline__ unsigned short f2bf(float x) {
  unsigned u = __float_as_uint(x);
  u += 0x7fffu + ((u >> 16) & 1u);   // round-to-nearest-even
  return (unsigned short)(u >> 16);
}
__device__ __forceinline__ float bf2f(unsigned short h) {
  return __uint_as_float(((unsigned)h) << 16);
}

// ---------------------------------------------------------------- softmax ---
// one block per row; 2048 rows total (p_s then p_t)
__global__ __launch_bounds__(256) void softmax_k(const float* __restrict__ ys,
                                                 const float* __restrict__ yt,
                                                 float* __restrict__ ps,
                                                 float* __restrict__ pt) {
  int bb = blockIdx.x;
  const float* src = (bb < NB * NN) ? ys : yt;
  float* dst       = (bb < NB * NN) ? ps : pt;
  int row = bb & (NB * NN - 1);
  const float* rp = src + (size_t)row * ND;
  float* wp = dst + (size_t)row * ND;
  int t = threadIdx.x;
  float a = rp[t];
  float b = rp[t + 256];
  float m = fmaxf(a, b);
  #pragma unroll
  for (int s = 1; s < 64; s <<= 1) m = fmaxf(m, __shfl_xor(m, s));
  __shared__ float red[4];
  int wid = t >> 6;
  if ((t & 63) == 0) red[wid] = m;
  __syncthreads();
  m = fmaxf(fmaxf(red[0], red[1]), fmaxf(red[2], red[3]));
  float e0 = expf((a - m) * 0.5f);   // softmax(y/2)
  float e1 = expf((b - m) * 0.5f);
  float ssum = e0 + e1;
  #pragma unroll
  for (int s = 1; s < 64; s <<= 1) ssum += __shfl_xor(ssum, s);
  __syncthreads();
  if ((t & 63) == 0) red[wid] = ssum;
  __syncthreads();
  ssum = red[0] + red[1] + red[2] + red[3];
  float inv = 1.0f / ssum;
  wp[t] = e0 * inv;
  wp[t + 256] = e1 * inv;
}

// ------------------------------------------------------------ cost matrix ---
// W[b][i][j] = sum_d |ps[b,i,d] - pt[b,j,d]|.  32x32 tile per WG, full D in LDS.
__global__ __launch_bounds__(256) void cost_k(const float* __restrict__ ps,
                                              const float* __restrict__ pt,
                                              float* __restrict__ W) {
  __shared__ float xs[32 * 512];
  __shared__ float ysh[32 * 512];
  int b  = blockIdx.z;
  int It = blockIdx.y * 32;
  int Jt = blockIdx.x * 32;
  int t = threadIdx.x;
  const float4* xg = reinterpret_cast<const float4*>(ps + ((size_t)b * NN + It) * ND);
  const float4* yg = reinterpret_cast<const float4*>(pt + ((size_t)b * NN + Jt) * ND);
  float4* xsv = reinterpret_cast<float4*>(xs);
  float4* ysv = reinterpret_cast<float4*>(ysh);
  // load 32x512 fp32 each side, quad-swizzled: quad q of row r stored at q ^ ((r>>1)&7)
  #pragma unroll
  for (int s = 0; s < 16; ++s) {
    int idx = s * 256 + t;       // quad index 0..4095 (= r*128 + q)
    int r = idx >> 7;
    int q = idx & 127;
    int qs = q ^ ((r >> 1) & 7);
    xsv[r * 128 + qs] = xg[idx];
    ysv[r * 128 + qs] = yg[idx];
  }
  __syncthreads();
  int tx = t & 15, ty = t >> 4;
  int i0 = ty * 2, j0 = tx * 2;
  int sx = ty & 7;               // = (i0>>1)&7, shared by rows i0,i0+1
  int sy = tx & 7;
  float a00 = 0.f, a01 = 0.f, a10 = 0.f, a11 = 0.f;
  for (int q = 0; q < 128; ++q) {
    float4 x0 = xsv[i0 * 128 + (q ^ sx)];
    float4 x1 = xsv[(i0 + 1) * 128 + (q ^ sx)];
    float4 y0 = ysv[j0 * 128 + (q ^ sy)];
    float4 y1 = ysv[(j0 + 1) * 128 + (q ^ sy)];
    a00 += fabsf(x0.x - y0.x) + fabsf(x0.y - y0.y) + fabsf(x0.z - y0.z) + fabsf(x0.w - y0.w);
    a01 += fabsf(x0.x - y1.x) + fabsf(x0.y - y1.y) + fabsf(x0.z - y1.z) + fabsf(x0.w - y1.w);
    a10 += fabsf(x1.x - y0.x) + fabsf(x1.y - y0.y) + fabsf(x1.z - y0.z) + fabsf(x1.w - y0.w);
    a11 += fabsf(x1.x - y1.x) + fabsf(x1.y - y1.y) + fabsf(x1.z - y1.z) + fabsf(x1.w - y1.w);
  }
  size_t base = ((size_t)b * NN + It + i0) * NN + Jt + j0;
  W[base]          = a00;  W[base + 1]      = a01;
  W[base + NN]     = a10;  W[base + NN + 1] = a11;
}

// ---------------------------------------------------------------- sinkhorn ---
// P = diag(u) K diag(v) throughout; K bf16 in LDS with 8-elem XOR swizzle
// pj = j ^ ((i&7)<<3).  One WG per batch, 1024 threads.
__global__ __launch_bounds__(1024) void sink_k(const float* __restrict__ Wg,
                                               float* __restrict__ losses) {
  __shared__ __align__(16) unsigned short Kl[NN * NN];  // 128 KiB
  __shared__ __align__(16) float u[NN];
  __shared__ __align__(16) float v[NN];
  __shared__ __align__(16) float scr[8 * NN];           // 8 KiB
  int b = blockIdx.x;
  int t = threadIdx.x;
  const float4* W4 = reinterpret_cast<const float4*>(Wg + (size_t)b * NN * NN);

  // build K = exp(-min(W,10)/0.1) + 1e-8  (bf16)
  #pragma unroll
  for (int s = 0; s < 16; ++s) {
    int q = s * 1024 + t;        // float4 index
    int e = q * 4;
    int i = e >> 8;
    int j = e & 255;
    float4 w4 = W4[q];
    float k0 = __expf(fminf(w4.x, 10.0f) * -10.0f) + 1e-8f;
    float k1 = __expf(fminf(w4.y, 10.0f) * -10.0f) + 1e-8f;
    float k2 = __expf(fminf(w4.z, 10.0f) * -10.0f) + 1e-8f;
    float k3 = __expf(fminf(w4.w, 10.0f) * -10.0f) + 1e-8f;
    int pj = j ^ ((i & 7) << 3);
    ushort4 kk;
    kk.x = f2bf(k0); kk.y = f2bf(k1); kk.z = f2bf(k2); kk.w = f2bf(k3);
    *reinterpret_cast<ushort4*>(&Kl[i * 256 + pj]) = kk;
  }
  if (t < NN) { u[t] = 1.0f; v[t] = 1.0f; }
  __syncthreads();

  for (int it = 0; it < NITER; ++it) {
    // ---- row pass: r_i = sum_j K[i][j] v[j];  u_i <- u_i / max(u_i*r_i, eps)
    {
      int i = t & 255, c = t >> 8;            // wave-uniform c (4 chunks of 64 j)
      const int rowb = i * 256;
      const int sw = (i & 7) << 3;
      float acc = 0.0f;
      #pragma unroll
      for (int q = 0; q < 8; ++q) {
        int j0 = c * 64 + q * 8;
        float4 va = *reinterpret_cast<const float4*>(&v[j0]);      // broadcast
        float4 vb = *reinterpret_cast<const float4*>(&v[j0 + 4]);  // broadcast
        ushort8v k8 = *reinterpret_cast<const ushort8v*>(&Kl[rowb + (j0 ^ sw)]);
        acc += bf2f(k8[0]) * va.x + bf2f(k8[1]) * va.y +
               bf2f(k8[2]) * va.z + bf2f(k8[3]) * va.w +
               bf2f(k8[4]) * vb.x + bf2f(k8[5]) * vb.y +
               bf2f(k8[6]) * vb.z + bf2f(k8[7]) * vb.w;
      }
      scr[c * 256 + i] = acc;
    }
    __syncthreads();
    if (t < NN) {
      float r = scr[t] + scr[256 + t] + scr[512 + t] + scr[768 + t];
      float uo = u[t];
      u[t] = uo / fmaxf(uo * r, 1e-8f);
    }
    __syncthreads();
    // ---- col pass: c_j = sum_i K[i][j] u[i];  v_j <- v_j / max(v_j*c_j, eps)
    {
      int j2 = t & 127, c = t >> 7;           // cols {2j2,2j2+1}, i in [32c,32c+32)
      float acc0 = 0.0f, acc1 = 0.0f;
      #pragma unroll
      for (int q = 0; q < 8; ++q) {
        int ib = c * 32 + q * 4;
        float4 uq = *reinterpret_cast<const float4*>(&u[ib]);      // broadcast
        {
          int i = ib + 0;
          unsigned dw = *reinterpret_cast<const unsigned*>(&Kl[i * 256 + ((2 * j2) ^ ((i & 7) << 3))]);
          acc0 += __uint_as_float(dw << 16) * uq.x;
          acc1 += __uint_as_float(dw & 0xffff0000u) * uq.x;
        }
        {
          int i = ib + 1;
          unsigned dw = *reinterpret_cast<const unsigned*>(&Kl[i * 256 + ((2 * j2) ^ ((i & 7) << 3))]);
          acc0 += __uint_as_float(dw << 16) * uq.y;
          acc1 += __uint_as_float(dw & 0xffff0000u) * uq.y;
        }
        {
          int i = ib + 2;
          unsigned dw = *reinterpret_cast<const unsigned*>(&Kl[i * 256 + ((2 * j2) ^ ((i & 7) << 3))]);
          acc0 += __uint_as_float(dw << 16) * uq.z;
          acc1 += __uint_as_float(dw & 0xffff0000u) * uq.z;
        }
        {
          int i = ib + 3;
          unsigned dw = *reinterpret_cast<const unsigned*>(&Kl[i * 256 + ((2 * j2) ^ ((i & 7) << 3))]);
          acc0 += __uint_as_float(dw << 16) * uq.w;
          acc1 += __uint_as_float(dw & 0xffff0000u) * uq.w;
        }
      }
      *reinterpret_cast<float2*>(&scr[c * 256 + 2 * j2]) = make_float2(acc0, acc1);
    }
    __syncthreads();
    if (t < NN) {
      float s0 = 0.0f;
      #pragma unroll
      for (int c = 0; c < 8; ++c) s0 += scr[c * 256 + t];
      float vo = v[t];
      v[t] = vo / fmaxf(vo * s0, 1e-8f);
    }
    __syncthreads();
  }

  // ---- loss = sum_ij u_i K_ij v_j W_ij  (original, unclipped W)
  float acc = 0.0f;
  #pragma unroll
  for (int s = 0; s < 16; ++s) {
    int q = s * 1024 + t;
    int e = q * 4;
    int i = e >> 8;
    int j = e & 255;
    float4 w4 = W4[q];
    int pj = j ^ ((i & 7) << 3);
    ushort4 k4 = *reinterpret_cast<const ushort4*>(&Kl[i * 256 + pj]);
    float4 v4 = *reinterpret_cast<const float4*>(&v[j]);
    float ui = u[i];
    acc += ui * (bf2f(k4.x) * v4.x * w4.x + bf2f(k4.y) * v4.y * w4.y +
                 bf2f(k4.z) * v4.z * w4.z + bf2f(k4.w) * v4.w * w4.w);
  }
  #pragma unroll
  for (int s = 1; s < 64; s <<= 1) acc += __shfl_xor(acc, s);
  __syncthreads();
  if ((t & 63) == 0) scr[t >> 6] = acc;
  __syncthreads();
  if (t == 0) {
    float tot = 0.0f;
    #pragma unroll
    for (int w = 0; w < 16; ++w) tot += scr[w];
    losses[b] = tot;
  }
}

// ------------------------------------------------------------------ final ---
__global__ void final_k(const float* __restrict__ losses, float* __restrict__ out) {
  if (threadIdx.x == 0 && blockIdx.x == 0) {
    out[0] = 0.001f * 0.25f * (losses[0] + losses[1] + losses[2] + losses[3]);
  }
}

// ----------------------------------------------------------------- launch ---
extern "C" void kernel_launch(void* const* d_in, const int* in_sizes, int n_in,
                              void* d_out, int out_size, void* d_ws, size_t ws_size,
                              hipStream_t stream) {
  const float* ys = (const float*)d_in[0];
  const float* yt = (const float*)d_in[1];
  float* ws = (float*)d_ws;
  float* ps = ws;                                // 4*256*512
  float* pt = ps + (size_t)NB * NN * ND;         // 4*256*512
  float* W  = pt + (size_t)NB * NN * ND;         // 4*256*256
  float* losses = W + (size_t)NB * NN * NN;      // 4
  float* out = (float*)d_out;

  softmax_k<<<2 * NB * NN, 256, 0, stream>>>(ys, yt, ps, pt);
  cost_k<<<dim3(8, 8, NB), 256, 0, stream>>>(ps, pt, W);
  sink_k<<<NB, 1024, 0, stream>>>(W, losses);
  final_k<<<1, 64, 0, stream>>>(losses, out);
}

// Round 6
// 107.911 us; speedup vs baseline: 1.0444x; 1.0444x over previous
//
#include <hip/hip_runtime.h>

#define NB 4
#define NN 256
#define ND 512
#define NITER 10

typedef _Float16 half_t;
typedef __attribute__((ext_vector_type(8))) unsigned short ushort8v;
typedef __attribute__((ext_vector_type(8))) _Float16 half8v;
typedef __attribute__((ext_vector_type(2))) _Float16 half2v;

__device__ __forceinline__ unsigned short f2bf(float x) {
  unsigned u = __float_as_uint(x);
  u += 0x7fffu + ((u >> 16) & 1u);   // round-to-nearest-even
  return (unsigned short)(u >> 16);
}
__device__ __forceinline__ float bf2f(unsigned short h) {
  return __uint_as_float(((unsigned)h) << 16);
}

// ---------------------------------------------------------------- softmax ---
// one block per row; 2048 rows total (p_s then p_t). fp16 output.
// Block 0 also zeroes d_out (stream-ordered before sink_k's atomicAdd).
__global__ __launch_bounds__(256) void softmax_k(const float* __restrict__ ys,
                                                 const float* __restrict__ yt,
                                                 half_t* __restrict__ ps,
                                                 half_t* __restrict__ pt,
                                                 float* __restrict__ out) {
  int bb = blockIdx.x;
  if (bb == 0 && threadIdx.x == 0) out[0] = 0.0f;
  const float* src = (bb < NB * NN) ? ys : yt;
  half_t* dst      = (bb < NB * NN) ? ps : pt;
  int row = bb & (NB * NN - 1);
  const float* rp = src + (size_t)row * ND;
  half_t* wp = dst + (size_t)row * ND;
  int t = threadIdx.x;
  float a = rp[t];
  float b = rp[t + 256];
  float m = fmaxf(a, b);
  #pragma unroll
  for (int s = 1; s < 64; s <<= 1) m = fmaxf(m, __shfl_xor(m, s));
  __shared__ float red[4];
  int wid = t >> 6;
  if ((t & 63) == 0) red[wid] = m;
  __syncthreads();
  m = fmaxf(fmaxf(red[0], red[1]), fmaxf(red[2], red[3]));
  float e0 = expf((a - m) * 0.5f);   // softmax(y/2)
  float e1 = expf((b - m) * 0.5f);
  float ssum = e0 + e1;
  #pragma unroll
  for (int s = 1; s < 64; s <<= 1) ssum += __shfl_xor(ssum, s);
  __syncthreads();
  if ((t & 63) == 0) red[wid] = ssum;
  __syncthreads();
  ssum = red[0] + red[1] + red[2] + red[3];
  float inv = 1.0f / ssum;
  wp[t]       = (half_t)(e0 * inv);
  wp[t + 256] = (half_t)(e1 * inv);
}

// ------------------------------------------------------------ cost matrix ---
// W[b][i][j] = sum_d |ps[b,i,d] - pt[b,j,d]|, fp16 in / fp16 out.
// 32x32 tile per WG, full D staged in LDS as fp16 (32KB/side).
// Quad (16B) rotation swizzle: quad q of row r at (q + rot(r)) & 63,
// rot(r) = (r + (r>>3)) & 7  -> compute-phase reads spread across banks.
__global__ __launch_bounds__(256) void cost_k(const half_t* __restrict__ ps,
                                              const half_t* __restrict__ pt,
                                              half_t* __restrict__ W) {
  __shared__ half_t xs[32 * 512];   // 32 KiB
  __shared__ half_t ysh[32 * 512];  // 32 KiB
  int b  = blockIdx.z;
  int It = blockIdx.y * 32;
  int Jt = blockIdx.x * 32;
  int t = threadIdx.x;
  const half8v* xg = reinterpret_cast<const half8v*>(ps + ((size_t)b * NN + It) * ND);
  const half8v* yg = reinterpret_cast<const half8v*>(pt + ((size_t)b * NN + Jt) * ND);
  half8v* xsv = reinterpret_cast<half8v*>(xs);
  half8v* ysv = reinterpret_cast<half8v*>(ysh);
  #pragma unroll
  for (int s = 0; s < 8; ++s) {
    int qidx = s * 256 + t;        // quad index 0..2047 (= r*64 + q)
    int r = qidx >> 6;
    int q = qidx & 63;
    int rot = (r + (r >> 3)) & 7;
    int dst = r * 64 + ((q + rot) & 63);
    xsv[dst] = xg[qidx];
    ysv[dst] = yg[qidx];
  }
  __syncthreads();
  int tx = t & 15, ty = t >> 4;
  int i0 = 2 * ty, j0 = 2 * tx;
  int rx0 = (i0 + (i0 >> 3)) & 7;
  int rx1 = ((i0 + 1) + ((i0 + 1) >> 3)) & 7;
  int ry0 = (j0 + (j0 >> 3)) & 7;
  int ry1 = ((j0 + 1) + ((j0 + 1) >> 3)) & 7;
  float a00 = 0.f, a01 = 0.f, a10 = 0.f, a11 = 0.f;
  #pragma unroll 4
  for (int qq = 0; qq < 64; ++qq) {
    half8v x0 = xsv[i0 * 64 + ((qq + rx0) & 63)];
    half8v x1 = xsv[(i0 + 1) * 64 + ((qq + rx1) & 63)];
    half8v y0 = ysv[j0 * 64 + ((qq + ry0) & 63)];
    half8v y1 = ysv[(j0 + 1) * 64 + ((qq + ry1) & 63)];
    #pragma unroll
    for (int e = 0; e < 8; ++e) {
      float xf0 = (float)x0[e], xf1 = (float)x1[e];
      float yf0 = (float)y0[e], yf1 = (float)y1[e];
      a00 += fabsf(xf0 - yf0);
      a01 += fabsf(xf0 - yf1);
      a10 += fabsf(xf1 - yf0);
      a11 += fabsf(xf1 - yf1);
    }
  }
  half_t* wb = W + ((size_t)b * NN + It + i0) * NN + Jt + j0;
  half2v w0; w0[0] = (half_t)a00; w0[1] = (half_t)a01;
  half2v w1; w1[0] = (half_t)a10; w1[1] = (half_t)a11;
  *reinterpret_cast<half2v*>(wb)      = w0;
  *reinterpret_cast<half2v*>(wb + NN) = w1;
}

// ---------------------------------------------------------------- sinkhorn ---
// P = diag(u) K diag(v); K bf16 in LDS, 8-elem XOR swizzle pj = j ^ ((i&7)<<3).
// One WG per batch, 1024 threads. W input fp16. Loss atomicAdd'd to out.
__global__ __launch_bounds__(1024) void sink_k(const half_t* __restrict__ Wg,
                                               float* __restrict__ out) {
  __shared__ __align__(16) unsigned short Kl[NN * NN];  // 128 KiB
  __shared__ __align__(16) float u[NN];
  __shared__ __align__(16) float v[NN];
  __shared__ __align__(16) float scr[16 * NN];          // 16 KiB
  int b = blockIdx.x;
  int t = threadIdx.x;
  const half8v* W8 = reinterpret_cast<const half8v*>(Wg + (size_t)b * NN * NN);

  // build K = exp(-min(W,10)/0.1) + 1e-8  (bf16)
  #pragma unroll
  for (int s = 0; s < 8; ++s) {
    int q8 = s * 1024 + t;       // 8-elem group index 0..8191
    int e = q8 * 8;
    int i = e >> 8;
    int j = e & 255;
    half8v w8 = W8[q8];
    ushort8v kk;
    #pragma unroll
    for (int r = 0; r < 8; ++r) {
      float kf = __expf(fminf((float)w8[r], 10.0f) * -10.0f) + 1e-8f;
      kk[r] = f2bf(kf);
    }
    *reinterpret_cast<ushort8v*>(&Kl[i * 256 + (j ^ ((i & 7) << 3))]) = kk;
  }
  if (t < NN) { u[t] = 1.0f; v[t] = 1.0f; }
  __syncthreads();

  for (int it = 0; it < NITER; ++it) {
    // ---- row pass: r_i = sum_j K[i][j] v[j]
    {
      int i = t & 255, c = t >> 8;            // c wave-uniform
      const int rowb = i * 256;
      const int sw = (i & 7) << 3;
      float acc = 0.0f;
      #pragma unroll
      for (int q = 0; q < 8; ++q) {
        int j0 = c * 64 + q * 8;
        float4 va = *reinterpret_cast<const float4*>(&v[j0]);      // broadcast
        float4 vb = *reinterpret_cast<const float4*>(&v[j0 + 4]);  // broadcast
        ushort8v k8 = *reinterpret_cast<const ushort8v*>(&Kl[rowb + (j0 ^ sw)]);
        acc += bf2f(k8[0]) * va.x + bf2f(k8[1]) * va.y +
               bf2f(k8[2]) * va.z + bf2f(k8[3]) * va.w +
               bf2f(k8[4]) * vb.x + bf2f(k8[5]) * vb.y +
               bf2f(k8[6]) * vb.z + bf2f(k8[7]) * vb.w;
      }
      scr[c * 256 + i] = acc;
    }
    __syncthreads();
    if (t < NN) {
      float r = scr[t] + scr[256 + t] + scr[512 + t] + scr[768 + t];
      float uo = u[t];
      u[t] = uo / fmaxf(uo * r, 1e-8f);
    }
    __syncthreads();
    // ---- col pass: c_j = sum_i K[i][j] u[i];  4 cols/thread via b64 reads
    {
      int j4 = t & 63, c = t >> 6;            // c in 0..15, wave-uniform
      int jc = 4 * j4;
      float acc0 = 0.f, acc1 = 0.f, acc2 = 0.f, acc3 = 0.f;
      #pragma unroll
      for (int q4 = 0; q4 < 4; ++q4) {
        int ib = c * 16 + q4 * 4;
        float4 uq = *reinterpret_cast<const float4*>(&u[ib]);      // broadcast
        {
          int i = ib + 0;
          ushort4 k4 = *reinterpret_cast<const ushort4*>(&Kl[i * 256 + (jc ^ ((i & 7) << 3))]);
          acc0 += bf2f(k4.x) * uq.x; acc1 += bf2f(k4.y) * uq.x;
          acc2 += bf2f(k4.z) * uq.x; acc3 += bf2f(k4.w) * uq.x;
        }
        {
          int i = ib + 1;
          ushort4 k4 = *reinterpret_cast<const ushort4*>(&Kl[i * 256 + (jc ^ ((i & 7) << 3))]);
          acc0 += bf2f(k4.x) * uq.y; acc1 += bf2f(k4.y) * uq.y;
          acc2 += bf2f(k4.z) * uq.y; acc3 += bf2f(k4.w) * uq.y;
        }
        {
          int i = ib + 2;
          ushort4 k4 = *reinterpret_cast<const ushort4*>(&Kl[i * 256 + (jc ^ ((i & 7) << 3))]);
          acc0 += bf2f(k4.x) * uq.z; acc1 += bf2f(k4.y) * uq.z;
          acc2 += bf2f(k4.z) * uq.z; acc3 += bf2f(k4.w) * uq.z;
        }
        {
          int i = ib + 3;
          ushort4 k4 = *reinterpret_cast<const ushort4*>(&Kl[i * 256 + (jc ^ ((i & 7) << 3))]);
          acc0 += bf2f(k4.x) * uq.w; acc1 += bf2f(k4.y) * uq.w;
          acc2 += bf2f(k4.z) * uq.w; acc3 += bf2f(k4.w) * uq.w;
        }
      }
      *reinterpret_cast<float4*>(&scr[c * 256 + jc]) = make_float4(acc0, acc1, acc2, acc3);
    }
    __syncthreads();
    if (t < NN) {
      float s0 = 0.0f;
      #pragma unroll
      for (int c = 0; c < 16; ++c) s0 += scr[c * 256 + t];
      float vo = v[t];
      v[t] = vo / fmaxf(vo * s0, 1e-8f);
    }
    __syncthreads();
  }

  // ---- loss = sum_ij u_i K_ij v_j W_ij  (W unclipped, fp16)
  float acc = 0.0f;
  #pragma unroll
  for (int s = 0; s < 8; ++s) {
    int q8 = s * 1024 + t;
    int e = q8 * 8;
    int i = e >> 8;
    int j = e & 255;
    half8v w8 = W8[q8];
    ushort8v k8 = *reinterpret_cast<const ushort8v*>(&Kl[i * 256 + (j ^ ((i & 7) << 3))]);
    float ui = u[i];
    float4 v0 = *reinterpret_cast<const float4*>(&v[j]);
    float4 v1 = *reinterpret_cast<const float4*>(&v[j + 4]);
    acc += ui * (bf2f(k8[0]) * v0.x * (float)w8[0] + bf2f(k8[1]) * v0.y * (float)w8[1] +
                 bf2f(k8[2]) * v0.z * (float)w8[2] + bf2f(k8[3]) * v0.w * (float)w8[3] +
                 bf2f(k8[4]) * v1.x * (float)w8[4] + bf2f(k8[5]) * v1.y * (float)w8[5] +
                 bf2f(k8[6]) * v1.z * (float)w8[6] + bf2f(k8[7]) * v1.w * (float)w8[7]);
  }
  #pragma unroll
  for (int s = 1; s < 64; s <<= 1) acc += __shfl_xor(acc, s);
  __syncthreads();
  if ((t & 63) == 0) scr[t >> 6] = acc;
  __syncthreads();
  if (t == 0) {
    float tot = 0.0f;
    #pragma unroll
    for (int w = 0; w < 16; ++w) tot += scr[w];
    atomicAdd(out, 2.5e-4f * tot);   // 0.001 * mean over 4 batches
  }
}

// ----------------------------------------------------------------- launch ---
extern "C" void kernel_launch(void* const* d_in, const int* in_sizes, int n_in,
                              void* d_out, int out_size, void* d_ws, size_t ws_size,
                              hipStream_t stream) {
  const float* ys = (const float*)d_in[0];
  const float* yt = (const float*)d_in[1];
  half_t* ps = (half_t*)d_ws;                    // 4*256*512 fp16 = 1 MiB
  half_t* pt = ps + (size_t)NB * NN * ND;        // 1 MiB
  half_t* W  = pt + (size_t)NB * NN * ND;        // 4*256*256 fp16 = 512 KiB
  float* out = (float*)d_out;

  softmax_k<<<2 * NB * NN, 256, 0, stream>>>(ys, yt, ps, pt, out);
  cost_k<<<dim3(8, 8, NB), 256, 0, stream>>>(ps, pt, W);
  sink_k<<<NB, 1024, 0, stream>>>(W, out);
}